// Round 10
// baseline (205.925 us; speedup 1.0000x reference)
//
#include <hip/hip_runtime.h>
#include <cstdint>

// Problem constants (fixed by the reference: B=64,S=512,IN=OUT=256,R=40,NB=3,E=262144)
#define N_NODES 32768
#define IN_F    256
#define OUT_F   256
#define NBASES  3
#define N_EDGES 262144
#define K_DIM   (NBASES * IN_F)    // 768: GEMM reduction dim (b*256 + i)

typedef __attribute__((ext_vector_type(8))) short bf16x8;
typedef __attribute__((ext_vector_type(4))) float f32x4;

__device__ __forceinline__ unsigned short f2bf(float x) {
    union { float f; unsigned int u; } c; c.f = x;
    unsigned int u = c.u;
    u = (u + 0x7FFFu + ((u >> 16) & 1u)) >> 16;   // round-to-nearest-even
    return (unsigned short)u;
}
__device__ __forceinline__ float bf2f(unsigned short h) {
    union { unsigned int u; float f; } c; c.u = ((unsigned int)h) << 16;
    return c.f;
}

// ---------------------------------------------------------------------------
// Prep (fused): blocks [0,8192) convert text f32 -> hb bf16; blocks
// [8192,8384) transpose bases -> Wt bf16; blocks [8384,8512) zero counts.
// ---------------------------------------------------------------------------
__global__ __launch_bounds__(256) void prep_kernel(
    const float* __restrict__ text,     // [N_NODES, 256] f32
    const float* __restrict__ bases,    // [768, 256] f32
    unsigned short* __restrict__ hb,    // [N_NODES, 256] bf16
    unsigned short* __restrict__ Wt,    // [256, 768] bf16
    int* __restrict__ counts)           // [N_NODES] -> zeroed
{
    const int tid = threadIdx.x;
    if (blockIdx.x < 8192) {
        int i = blockIdx.x * 256 + tid;            // float4 index
        float4 v = reinterpret_cast<const float4*>(text)[i];
        ushort4 o;
        o.x = f2bf(v.x); o.y = f2bf(v.y); o.z = f2bf(v.z); o.w = f2bf(v.w);
        reinterpret_cast<ushort4*>(hb)[i] = o;
    } else if (blockIdx.x < 8384) {
        int tb = blockIdx.x - 8192;                // [0,192)
        int kb = tb % 24, ob = tb / 24;            // 32-wide tiles
        __shared__ float tile[32][33];
        int c = tid & 31, r8 = tid >> 5;
        #pragma unroll
        for (int i = 0; i < 4; ++i) {
            int r = r8 + 8 * i;
            tile[r][c] = bases[(size_t)(kb * 32 + r) * OUT_F + ob * 32 + c];
        }
        __syncthreads();
        #pragma unroll
        for (int i = 0; i < 4; ++i) {
            int r = r8 + 8 * i;                    // output row within o-tile
            Wt[(size_t)(ob * 32 + r) * K_DIM + kb * 32 + c] = f2bf(tile[c][r]);
        }
    } else {
        int i = (blockIdx.x - 8384) * 256 + tid;   // [0, 32768)
        counts[i] = 0;
    }
}

// ---------------------------------------------------------------------------
// Counting sort of edges by dst: histogram -> scan -> scatter(packed int2)
// ---------------------------------------------------------------------------
__global__ __launch_bounds__(256) void hist_kernel(
    const int* __restrict__ dst, int* __restrict__ counts)
{
    int e4 = blockIdx.x * 256 + threadIdx.x;
    int4 d = reinterpret_cast<const int4*>(dst)[e4];
    atomicAdd(&counts[d.x], 1);
    atomicAdd(&counts[d.y], 1);
    atomicAdd(&counts[d.z], 1);
    atomicAdd(&counts[d.w], 1);
}

// Single block, 1024 threads, 32 counters each. Converts counts -> cursor
// in place and writes the exclusive-scan offsets.
__global__ __launch_bounds__(1024) void scan_kernel(
    int* __restrict__ counts,        // in: histogram; out: cursor (in place)
    int* __restrict__ offsets)       // [N_NODES+1]
{
    __shared__ int wsum[16];
    const int tid = threadIdx.x;
    const int wave = tid >> 6, lane = tid & 63;
    const int base = tid * 32;
    int local[32];
    int sum = 0;
    #pragma unroll
    for (int k8 = 0; k8 < 8; ++k8) {
        int4 v = reinterpret_cast<const int4*>(counts + base)[k8];
        local[k8 * 4 + 0] = v.x; local[k8 * 4 + 1] = v.y;
        local[k8 * 4 + 2] = v.z; local[k8 * 4 + 3] = v.w;
        sum += v.x + v.y + v.z + v.w;
    }
    int inc = sum;                            // wave-inclusive scan of sums
    #pragma unroll
    for (int off = 1; off < 64; off <<= 1) {
        int v = __shfl_up(inc, off);
        if (lane >= off) inc += v;
    }
    if (lane == 63) wsum[wave] = inc;
    __syncthreads();
    if (wave == 0 && lane < 16) {             // scan the 16 wave totals
        int v = wsum[lane];
        #pragma unroll
        for (int off = 1; off < 16; off <<= 1) {
            int u = __shfl_up(v, off);
            if (lane >= off) v += u;
        }
        wsum[lane] = v;
    }
    __syncthreads();
    int run = inc - sum + (wave ? wsum[wave - 1] : 0);   // exclusive prefix
    #pragma unroll
    for (int k = 0; k < 32; ++k) {
        offsets[base + k] = run;
        counts[base + k] = run;               // cursor
        run += local[k];
    }
    if (tid == 1023) offsets[N_NODES] = run;  // == N_EDGES
}

// Packs per-edge (src, bf16(comp[rel,0..2])) so agg needs no comp lookups
// and invalid lanes (coef=0) are harmless.
__global__ __launch_bounds__(256) void scatter_kernel(
    const int* __restrict__ dst, const int* __restrict__ src,
    const int* __restrict__ rel, const float* __restrict__ comp,
    int* __restrict__ cursor, int2* __restrict__ packed2)
{
    int e4 = blockIdx.x * 256 + threadIdx.x;
    int4 d = reinterpret_cast<const int4*>(dst)[e4];
    int4 s = reinterpret_cast<const int4*>(src)[e4];
    int4 r = reinterpret_cast<const int4*>(rel)[e4];
    int dd[4] = { d.x, d.y, d.z, d.w };
    int ss[4] = { s.x, s.y, s.z, s.w };
    int rr[4] = { r.x, r.y, r.z, r.w };
    #pragma unroll
    for (int q = 0; q < 4; ++q) {
        float c0 = comp[rr[q] * 3 + 0];
        float c1 = comp[rr[q] * 3 + 1];
        float c2 = comp[rr[q] * 3 + 2];
        int w0 = ss[q] | ((int)f2bf(c0) << 16);
        int w1 = (int)f2bf(c1) | ((int)f2bf(c2) << 16);
        int pos = atomicAdd(&cursor[dd[q]], 1);
        packed2[pos] = make_int2(w0, w1);
    }
}

// ---------------------------------------------------------------------------
// Aggregation in INPUT space: z[n, b, i] = sum_{e: dst=n} comp[rel_e,b]*h[src_e,i]
// One wave per dst node; lane owns 4 input features; 8-deep gather pipeline
// (mask-folded coefs, no tail branches). LDS-free -> max occupancy.
// ---------------------------------------------------------------------------
__global__ __launch_bounds__(256) void agg_kernel(
    const unsigned short* __restrict__ hb,    // [N_NODES, 256] bf16
    const int2* __restrict__ packed2,         // sorted by dst
    const int* __restrict__ offsets,          // [N_NODES+1]
    unsigned short* __restrict__ z)           // [N_NODES, 768] bf16
{
    const int node = blockIdx.x * 4 + (threadIdx.x >> 6);
    const int lane = threadIdx.x & 63;
    const int start = offsets[node];
    const int end   = offsets[node + 1];

    float a0[4] = {}, a1[4] = {}, a2[4] = {};
    const unsigned short* hp = hb + lane * 4;

    for (int cb = start; cb < end; cb += 64) {
        int idx = cb + lane;
        int wx = 0, wy = 0;                       // coef 0 for idx >= end
        if (idx < end) { int2 w = packed2[idx]; wx = w.x; wy = w.y; }
        int cnt = min(64, end - cb);
        for (int j = 0; j < cnt; j += 8) {
            float c0[8], c1[8], c2[8];
            ushort4 u[8];
            #pragma unroll
            for (int q = 0; q < 8; ++q) {         // 8 gathers in flight
                int p0 = __shfl(wx, j + q);
                int p1 = __shfl(wy, j + q);
                int s = p0 & 0xFFFF;
                float m = (j + q < cnt) ? 1.f : 0.f;
                c0[q] = m * bf2f((unsigned short)((unsigned)p0 >> 16));
                c1[q] = m * bf2f((unsigned short)(p1 & 0xFFFF));
                c2[q] = m * bf2f((unsigned short)((unsigned)p1 >> 16));
                u[q] = *reinterpret_cast<const ushort4*>(hp + (size_t)s * IN_F);
            }
            #pragma unroll
            for (int q = 0; q < 8; ++q) {
                float v[4] = { bf2f(u[q].x), bf2f(u[q].y),
                               bf2f(u[q].z), bf2f(u[q].w) };
                #pragma unroll
                for (int k = 0; k < 4; ++k) {
                    a0[k] += c0[q] * v[k];
                    a1[k] += c1[q] * v[k];
                    a2[k] += c2[q] * v[k];
                }
            }
        }
    }

    unsigned short* zp = z + (size_t)node * K_DIM + lane * 4;
    ushort4 o;
    o.x = f2bf(a0[0]); o.y = f2bf(a0[1]); o.z = f2bf(a0[2]); o.w = f2bf(a0[3]);
    *reinterpret_cast<ushort4*>(zp) = o;
    o.x = f2bf(a1[0]); o.y = f2bf(a1[1]); o.z = f2bf(a1[2]); o.w = f2bf(a1[3]);
    *reinterpret_cast<ushort4*>(zp + 256) = o;
    o.x = f2bf(a2[0]); o.y = f2bf(a2[1]); o.z = f2bf(a2[2]); o.w = f2bf(a2[3]);
    *reinterpret_cast<ushort4*>(zp + 512) = o;
}

// ---------------------------------------------------------------------------
// GEMM: out[m, o] = relu( sum_k z[m,k] * Wt[o,k] + bias[o] )
// M=32768, N=256, K=768. 128x128 tile, 4 waves (2x2), MFMA 16x16x32.
// NO LDS, NO BARRIERS: with row-major bf16 operands, a wave's MFMA fragment
// (A[m=l16][k=quad*8+j]) is a direct global_load_dwordx4 at row*1536+oct*16.
// Per BK=64 step each z row consumes exactly one 128-B line (100% line use);
// Wt (0.4 MB) is L2-resident for all blocks. Software 2-stage register
// pipeline; hardware vmcnt scoreboard does fine-grained waiting (the
// restructured K-loop the 2-barrier LDS shape couldn't express).
// ---------------------------------------------------------------------------
__global__ __launch_bounds__(256) void gemm_kernel(
    const unsigned short* __restrict__ A,   // z  [32768, 768] bf16
    const unsigned short* __restrict__ Bt,  // Wt [256, 768] bf16
    const float* __restrict__ bias,         // [256]
    float* __restrict__ out)                // [32768, 256] f32
{
    const int tid  = threadIdx.x;
    const int wave = tid >> 6, lane = tid & 63;
    const int quad = lane >> 4, l16 = lane & 15;
    const int wm = (wave & 1) * 64, wn = (wave >> 1) * 64;
    const int m0 = blockIdx.x * 128, n0 = blockIdx.y * 128;

    f32x4 acc[4][4] = {};

    // Fragment base pointers: lane (quad,l16) of row-group i reads 16 B at
    // (row_base + i*16)*K_DIM + c*32 + quad*8.
    const unsigned short* ap = A  + (size_t)(m0 + wm + l16) * K_DIM + quad * 8;
    const unsigned short* bp = Bt + (size_t)(n0 + wn + l16) * K_DIM + quad * 8;

    bf16x8 a0[4], b0[4];
    #pragma unroll
    for (int i = 0; i < 4; ++i) {
        a0[i] = *reinterpret_cast<const bf16x8*>(ap + (size_t)i * 16 * K_DIM);
        b0[i] = *reinterpret_cast<const bf16x8*>(bp + (size_t)i * 16 * K_DIM);
    }

    for (int c = 0; c < K_DIM / 32; ++c) {        // 24 chunks of 32-k
        // Prefetch chunk c+1 (clamped; last prefetch is redundant-but-harmless)
        int off = (c + 1 < K_DIM / 32 ? c + 1 : c) * 32;
        bf16x8 a1[4], b1[4];
        #pragma unroll
        for (int i = 0; i < 4; ++i) {
            a1[i] = *reinterpret_cast<const bf16x8*>(
                ap + (size_t)i * 16 * K_DIM + off);
            b1[i] = *reinterpret_cast<const bf16x8*>(
                bp + (size_t)i * 16 * K_DIM + off);
        }
        #pragma unroll
        for (int i = 0; i < 4; ++i)
            #pragma unroll
            for (int j = 0; j < 4; ++j)
                acc[i][j] = __builtin_amdgcn_mfma_f32_16x16x32_bf16(
                    a0[i], b0[j], acc[i][j], 0, 0, 0);
        #pragma unroll
        for (int i = 0; i < 4; ++i) { a0[i] = a1[i]; b0[i] = b1[i]; }
    }

    // Epilogue: C/D layout col = l16, row = quad*4 + r. Fused bias + ReLU.
    #pragma unroll
    for (int j = 0; j < 4; ++j) {
        int col = n0 + wn + j * 16 + l16;
        float bv = bias[col];
        #pragma unroll
        for (int i = 0; i < 4; ++i) {
            int row_base = m0 + wm + i * 16 + quad * 4;
            #pragma unroll
            for (int r = 0; r < 4; ++r)
                out[(size_t)(row_base + r) * OUT_F + col] =
                    fmaxf(acc[i][j][r] + bv, 0.f);
        }
    }
}

extern "C" void kernel_launch(void* const* d_in, const int* in_sizes, int n_in,
                              void* d_out, int out_size, void* d_ws, size_t ws_size,
                              hipStream_t stream) {
    const float* text  = (const float*)d_in[0];   // [64,512,256] f32
    const int*   src   = (const int*)d_in[1];     // [E]
    const int*   dst   = (const int*)d_in[2];     // [E]
    const int*   rel   = (const int*)d_in[3];     // [E]
    const float* bases = (const float*)d_in[4];   // [3,256,256] f32 = [768,256]
    const float* comp  = (const float*)d_in[5];   // [40,3] f32
    const float* bias  = (const float*)d_in[6];   // [256] f32
    float* out = (float*)d_out;

    // Workspace layout (~70 MB; all chunks 16B-aligned):
    //   z       : N*768*2   = 50,331,648 B
    //   hb      : N*256*2   = 16,777,216 B
    //   packed2 : E*8       =  2,097,152 B
    //   offsets : (N+4)*4   =    131,088 B
    //   counts  : N*4       =    131,072 B
    //   Wt      : 256*768*2 =    393,216 B
    char* p = (char*)d_ws;
    unsigned short* z  = (unsigned short*)p;      p += (size_t)N_NODES * K_DIM * 2;
    unsigned short* hb = (unsigned short*)p;      p += (size_t)N_NODES * IN_F * 2;
    int2* packed2 = (int2*)p;                     p += (size_t)N_EDGES * 8;
    int* offsets  = (int*)p;                      p += (size_t)(N_NODES + 4) * 4;
    int* counts   = (int*)p;                      p += (size_t)N_NODES * 4;
    unsigned short* Wt = (unsigned short*)p;

    prep_kernel<<<8512, 256, 0, stream>>>(text, bases, hb, Wt, counts);
    hist_kernel<<<N_EDGES / 1024, 256, 0, stream>>>(dst, counts);
    scan_kernel<<<1, 1024, 0, stream>>>(counts, offsets);
    scatter_kernel<<<N_EDGES / 1024, 256, 0, stream>>>(
        dst, src, rel, comp, counts, packed2);
    agg_kernel<<<N_NODES / 4, 256, 0, stream>>>(hb, packed2, offsets, z);
    gemm_kernel<<<dim3(N_NODES / 128, OUT_F / 128), 256, 0, stream>>>(
        z, Wt, bias, out);
}

// Round 11
// 177.356 us; speedup vs baseline: 1.1611x; 1.1611x over previous
//
#include <hip/hip_runtime.h>
#include <cstdint>

// Problem constants (fixed by the reference: B=64,S=512,IN=OUT=256,R=40,NB=3,E=262144)
#define N_NODES 32768
#define IN_F    256
#define OUT_F   256
#define NBASES  3
#define N_EDGES 262144
#define K_DIM   (NBASES * IN_F)    // 768: GEMM reduction dim (b*256 + i)

typedef __attribute__((ext_vector_type(8))) short bf16x8;
typedef __attribute__((ext_vector_type(4))) float f32x4;

__device__ __forceinline__ unsigned short f2bf(float x) {
    union { float f; unsigned int u; } c; c.f = x;
    unsigned int u = c.u;
    u = (u + 0x7FFFu + ((u >> 16) & 1u)) >> 16;   // round-to-nearest-even
    return (unsigned short)u;
}
__device__ __forceinline__ float bf2f(unsigned short h) {
    union { unsigned int u; float f; } c; c.u = ((unsigned int)h) << 16;
    return c.f;
}

__device__ __forceinline__ void async_copy16(const void* g, void* l) {
    __builtin_amdgcn_global_load_lds(
        (const __attribute__((address_space(1))) unsigned int*)g,
        (__attribute__((address_space(3))) unsigned int*)l, 16, 0, 0);
}

// ---------------------------------------------------------------------------
// Prep (fused): blocks [0,8192) convert text f32 -> hb bf16; blocks
// [8192,8384) transpose bases -> Wt bf16; blocks [8384,8512) zero counts.
// ---------------------------------------------------------------------------
__global__ __launch_bounds__(256) void prep_kernel(
    const float* __restrict__ text,     // [N_NODES, 256] f32
    const float* __restrict__ bases,    // [768, 256] f32
    unsigned short* __restrict__ hb,    // [N_NODES, 256] bf16
    unsigned short* __restrict__ Wt,    // [256, 768] bf16
    int* __restrict__ counts)           // [N_NODES] -> zeroed
{
    const int tid = threadIdx.x;
    if (blockIdx.x < 8192) {
        int i = blockIdx.x * 256 + tid;            // float4 index
        float4 v = reinterpret_cast<const float4*>(text)[i];
        ushort4 o;
        o.x = f2bf(v.x); o.y = f2bf(v.y); o.z = f2bf(v.z); o.w = f2bf(v.w);
        reinterpret_cast<ushort4*>(hb)[i] = o;
    } else if (blockIdx.x < 8384) {
        int tb = blockIdx.x - 8192;                // [0,192)
        int kb = tb % 24, ob = tb / 24;            // 32-wide tiles
        __shared__ float tile[32][33];
        int c = tid & 31, r8 = tid >> 5;
        #pragma unroll
        for (int i = 0; i < 4; ++i) {
            int r = r8 + 8 * i;
            tile[r][c] = bases[(size_t)(kb * 32 + r) * OUT_F + ob * 32 + c];
        }
        __syncthreads();
        #pragma unroll
        for (int i = 0; i < 4; ++i) {
            int r = r8 + 8 * i;                    // output row within o-tile
            Wt[(size_t)(ob * 32 + r) * K_DIM + kb * 32 + c] = f2bf(tile[c][r]);
        }
    } else {
        int i = (blockIdx.x - 8384) * 256 + tid;   // [0, 32768)
        counts[i] = 0;
    }
}

// ---------------------------------------------------------------------------
// Counting sort of edges by dst: histogram -> scan -> scatter(packed int2)
// ---------------------------------------------------------------------------
__global__ __launch_bounds__(256) void hist_kernel(
    const int* __restrict__ dst, int* __restrict__ counts)
{
    int e4 = blockIdx.x * 256 + threadIdx.x;
    int4 d = reinterpret_cast<const int4*>(dst)[e4];
    atomicAdd(&counts[d.x], 1);
    atomicAdd(&counts[d.y], 1);
    atomicAdd(&counts[d.z], 1);
    atomicAdd(&counts[d.w], 1);
}

// Single block, 1024 threads, 32 counters each. Converts counts -> cursor
// in place and writes the exclusive-scan offsets.
__global__ __launch_bounds__(1024) void scan_kernel(
    int* __restrict__ counts,        // in: histogram; out: cursor (in place)
    int* __restrict__ offsets)       // [N_NODES+1]
{
    __shared__ int wsum[16];
    const int tid = threadIdx.x;
    const int wave = tid >> 6, lane = tid & 63;
    const int base = tid * 32;
    int local[32];
    int sum = 0;
    #pragma unroll
    for (int k8 = 0; k8 < 8; ++k8) {
        int4 v = reinterpret_cast<const int4*>(counts + base)[k8];
        local[k8 * 4 + 0] = v.x; local[k8 * 4 + 1] = v.y;
        local[k8 * 4 + 2] = v.z; local[k8 * 4 + 3] = v.w;
        sum += v.x + v.y + v.z + v.w;
    }
    int inc = sum;                            // wave-inclusive scan of sums
    #pragma unroll
    for (int off = 1; off < 64; off <<= 1) {
        int v = __shfl_up(inc, off);
        if (lane >= off) inc += v;
    }
    if (lane == 63) wsum[wave] = inc;
    __syncthreads();
    if (wave == 0 && lane < 16) {             // scan the 16 wave totals
        int v = wsum[lane];
        #pragma unroll
        for (int off = 1; off < 16; off <<= 1) {
            int u = __shfl_up(v, off);
            if (lane >= off) v += u;
        }
        wsum[lane] = v;
    }
    __syncthreads();
    int run = inc - sum + (wave ? wsum[wave - 1] : 0);   // exclusive prefix
    #pragma unroll
    for (int k = 0; k < 32; ++k) {
        offsets[base + k] = run;
        counts[base + k] = run;               // cursor
        run += local[k];
    }
    if (tid == 1023) offsets[N_NODES] = run;  // == N_EDGES
}

// Packs per-edge (src, bf16(comp[rel,0..2])) so agg needs no comp lookups
// and invalid lanes (coef=0) are harmless.
__global__ __launch_bounds__(256) void scatter_kernel(
    const int* __restrict__ dst, const int* __restrict__ src,
    const int* __restrict__ rel, const float* __restrict__ comp,
    int* __restrict__ cursor, int2* __restrict__ packed2)
{
    int e4 = blockIdx.x * 256 + threadIdx.x;
    int4 d = reinterpret_cast<const int4*>(dst)[e4];
    int4 s = reinterpret_cast<const int4*>(src)[e4];
    int4 r = reinterpret_cast<const int4*>(rel)[e4];
    int dd[4] = { d.x, d.y, d.z, d.w };
    int ss[4] = { s.x, s.y, s.z, s.w };
    int rr[4] = { r.x, r.y, r.z, r.w };
    #pragma unroll
    for (int q = 0; q < 4; ++q) {
        float c0 = comp[rr[q] * 3 + 0];
        float c1 = comp[rr[q] * 3 + 1];
        float c2 = comp[rr[q] * 3 + 2];
        int w0 = ss[q] | ((int)f2bf(c0) << 16);
        int w1 = (int)f2bf(c1) | ((int)f2bf(c2) << 16);
        int pos = atomicAdd(&cursor[dd[q]], 1);
        packed2[pos] = make_int2(w0, w1);
    }
}

// ---------------------------------------------------------------------------
// Aggregation in INPUT space: z[n, b, i] = sum_{e: dst=n} comp[rel_e,b]*h[src_e,i]
// One wave per dst node; lane owns 4 input features; 8-deep gather pipeline
// (mask-folded coefs, no tail branches). LDS-free -> max occupancy.
// ---------------------------------------------------------------------------
__global__ __launch_bounds__(256) void agg_kernel(
    const unsigned short* __restrict__ hb,    // [N_NODES, 256] bf16
    const int2* __restrict__ packed2,         // sorted by dst
    const int* __restrict__ offsets,          // [N_NODES+1]
    unsigned short* __restrict__ z)           // [N_NODES, 768] bf16
{
    const int node = blockIdx.x * 4 + (threadIdx.x >> 6);
    const int lane = threadIdx.x & 63;
    const int start = offsets[node];
    const int end   = offsets[node + 1];

    float a0[4] = {}, a1[4] = {}, a2[4] = {};
    const unsigned short* hp = hb + lane * 4;

    for (int cb = start; cb < end; cb += 64) {
        int idx = cb + lane;
        int wx = 0, wy = 0;                       // coef 0 for idx >= end
        if (idx < end) { int2 w = packed2[idx]; wx = w.x; wy = w.y; }
        int cnt = min(64, end - cb);
        for (int j = 0; j < cnt; j += 8) {
            float c0[8], c1[8], c2[8];
            ushort4 u[8];
            #pragma unroll
            for (int q = 0; q < 8; ++q) {         // 8 gathers in flight
                int p0 = __shfl(wx, j + q);
                int p1 = __shfl(wy, j + q);
                int s = p0 & 0xFFFF;
                float m = (j + q < cnt) ? 1.f : 0.f;
                c0[q] = m * bf2f((unsigned short)((unsigned)p0 >> 16));
                c1[q] = m * bf2f((unsigned short)(p1 & 0xFFFF));
                c2[q] = m * bf2f((unsigned short)((unsigned)p1 >> 16));
                u[q] = *reinterpret_cast<const ushort4*>(hp + (size_t)s * IN_F);
            }
            #pragma unroll
            for (int q = 0; q < 8; ++q) {
                float v[4] = { bf2f(u[q].x), bf2f(u[q].y),
                               bf2f(u[q].z), bf2f(u[q].w) };
                #pragma unroll
                for (int k = 0; k < 4; ++k) {
                    a0[k] += c0[q] * v[k];
                    a1[k] += c1[q] * v[k];
                    a2[k] += c2[q] * v[k];
                }
            }
        }
    }

    unsigned short* zp = z + (size_t)node * K_DIM + lane * 4;
    ushort4 o;
    o.x = f2bf(a0[0]); o.y = f2bf(a0[1]); o.z = f2bf(a0[2]); o.w = f2bf(a0[3]);
    *reinterpret_cast<ushort4*>(zp) = o;
    o.x = f2bf(a1[0]); o.y = f2bf(a1[1]); o.z = f2bf(a1[2]); o.w = f2bf(a1[3]);
    *reinterpret_cast<ushort4*>(zp + 256) = o;
    o.x = f2bf(a2[0]); o.y = f2bf(a2[1]); o.z = f2bf(a2[2]); o.w = f2bf(a2[3]);
    *reinterpret_cast<ushort4*>(zp + 512) = o;
}

// ---------------------------------------------------------------------------
// GEMM: out[m, o] = relu( sum_k z[m,k] * Wt[o,k] + bias[o] )
// M=32768, N=256, K=768. 128x128 tile, 4 waves (2x2), MFMA 16x16x32.
// BK=64: 32 MFMAs per barrier (AITER ratio), 12 barriers total.
// DOUBLE-BUFFERED global_load_lds into XOR-swizzled [row][k-octet] LDS
// (8 octets/row, phys = oct ^ ((row>>1)&7): fragment-read banks = phys*4,
// 8 runs x 2 lanes = 2-way aliasing = free). 64 KB LDS; grid is 512 blocks
// = 2/CU, so the LDS increase costs no occupancy (m132 caveat inapplicable).
// R10 lesson: do NOT replace LDS staging with direct per-fragment global
// loads — they scatter 16 rows/instruction (poor coalescing) and serialize
// on vmcnt at 8 waves/CU (53 µs vs 22 µs).
// ---------------------------------------------------------------------------
__global__ __launch_bounds__(256) void gemm_kernel(
    const unsigned short* __restrict__ A,   // z  [32768, 768] bf16
    const unsigned short* __restrict__ Bt,  // Wt [256, 768] bf16
    const float* __restrict__ bias,         // [256]
    float* __restrict__ out)                // [32768, 256] f32
{
    __shared__ __align__(16) unsigned short As[2][128 * 64];   // 16 KB each
    __shared__ __align__(16) unsigned short Bs[2][128 * 64];

    const int tid  = threadIdx.x;
    const int wave = tid >> 6, lane = tid & 63;
    const int quad = lane >> 4, l16 = lane & 15;
    const int wm = (wave & 1) * 64, wn = (wave >> 1) * 64;
    const int m0 = blockIdx.x * 128, n0 = blockIdx.y * 128;

    f32x4 acc[4][4] = {};

    // Staging map: 1024 16-B slots per matrix per step; slot p <- logical
    // (row = p>>3, oct = (p&7)^((row>>1)&7)). 4 copies/thread per matrix.
    const unsigned short *ga[4], *gb[4];
    int lab[4];
    #pragma unroll
    for (int c = 0; c < 4; ++c) {
        int p = c * 256 + wave * 64 + lane;
        int row = p >> 3;
        int oct = (p & 7) ^ ((row >> 1) & 7);
        ga[c] = A  + (size_t)(m0 + row) * K_DIM + oct * 8;
        gb[c] = Bt + (size_t)(n0 + row) * K_DIM + oct * 8;
        lab[c] = (c * 256 + wave * 64) * 8;       // wave-uniform base (elems)
    }

    // Prologue: stage k=0 into buffer 0.
    #pragma unroll
    for (int c = 0; c < 4; ++c) {
        async_copy16(ga[c], &As[0][lab[c]]);
        async_copy16(gb[c], &Bs[0][lab[c]]);
    }

    int cur = 0;
    for (int step = 0; step < K_DIM / 64; ++step) {
        __syncthreads();   // own-copies drained (vmcnt0) -> buf[cur] ready;
                           // all waves done reading buf[cur^1] from step-1
        int k1 = (step + 1) * 64;
        if (k1 < K_DIM) {  // prefetch next slab; overlaps ds_read+MFMA below
            #pragma unroll
            for (int c = 0; c < 4; ++c) {
                async_copy16(ga[c] + k1, &As[cur ^ 1][lab[c]]);
                async_copy16(gb[c] + k1, &Bs[cur ^ 1][lab[c]]);
            }
        }

        #pragma unroll
        for (int s2 = 0; s2 < 2; ++s2) {          // two 32-k sub-steps
            bf16x8 af[4], bfr[4];
            #pragma unroll
            for (int i = 0; i < 4; ++i) {
                int row = wm + i * 16 + l16;
                int oph = (s2 * 4 + quad) ^ ((row >> 1) & 7);
                af[i] = *reinterpret_cast<const bf16x8*>(
                    &As[cur][(row * 8 + oph) * 8]);
                int nn   = wn + i * 16 + l16;
                int oph2 = (s2 * 4 + quad) ^ ((nn >> 1) & 7);
                bfr[i] = *reinterpret_cast<const bf16x8*>(
                    &Bs[cur][(nn * 8 + oph2) * 8]);
            }
            #pragma unroll
            for (int i = 0; i < 4; ++i)
                #pragma unroll
                for (int j = 0; j < 4; ++j)
                    acc[i][j] = __builtin_amdgcn_mfma_f32_16x16x32_bf16(
                        af[i], bfr[j], acc[i][j], 0, 0, 0);
        }
        cur ^= 1;
    }

    // Epilogue: C/D layout col = l16, row = quad*4 + r. Fused bias + ReLU.
    #pragma unroll
    for (int j = 0; j < 4; ++j) {
        int col = n0 + wn + j * 16 + l16;
        float bv = bias[col];
        #pragma unroll
        for (int i = 0; i < 4; ++i) {
            int row_base = m0 + wm + i * 16 + quad * 4;
            #pragma unroll
            for (int r = 0; r < 4; ++r)
                out[(size_t)(row_base + r) * OUT_F + col] =
                    fmaxf(acc[i][j][r] + bv, 0.f);
        }
    }
}

extern "C" void kernel_launch(void* const* d_in, const int* in_sizes, int n_in,
                              void* d_out, int out_size, void* d_ws, size_t ws_size,
                              hipStream_t stream) {
    const float* text  = (const float*)d_in[0];   // [64,512,256] f32
    const int*   src   = (const int*)d_in[1];     // [E]
    const int*   dst   = (const int*)d_in[2];     // [E]
    const int*   rel   = (const int*)d_in[3];     // [E]
    const float* bases = (const float*)d_in[4];   // [3,256,256] f32 = [768,256]
    const float* comp  = (const float*)d_in[5];   // [40,3] f32
    const float* bias  = (const float*)d_in[6];   // [256] f32
    float* out = (float*)d_out;

    // Workspace layout (~70 MB; all chunks 16B-aligned):
    //   z       : N*768*2   = 50,331,648 B
    //   hb      : N*256*2   = 16,777,216 B
    //   packed2 : E*8       =  2,097,152 B
    //   offsets : (N+4)*4   =    131,088 B
    //   counts  : N*4       =    131,072 B
    //   Wt      : 256*768*2 =    393,216 B
    char* p = (char*)d_ws;
    unsigned short* z  = (unsigned short*)p;      p += (size_t)N_NODES * K_DIM * 2;
    unsigned short* hb = (unsigned short*)p;      p += (size_t)N_NODES * IN_F * 2;
    int2* packed2 = (int2*)p;                     p += (size_t)N_EDGES * 8;
    int* offsets  = (int*)p;                      p += (size_t)(N_NODES + 4) * 4;
    int* counts   = (int*)p;                      p += (size_t)N_NODES * 4;
    unsigned short* Wt = (unsigned short*)p;

    prep_kernel<<<8512, 256, 0, stream>>>(text, bases, hb, Wt, counts);
    hist_kernel<<<N_EDGES / 1024, 256, 0, stream>>>(dst, counts);
    scan_kernel<<<1, 1024, 0, stream>>>(counts, offsets);
    scatter_kernel<<<N_EDGES / 1024, 256, 0, stream>>>(
        dst, src, rel, comp, counts, packed2);
    agg_kernel<<<N_NODES / 4, 256, 0, stream>>>(hb, packed2, offsets, z);
    gemm_kernel<<<dim3(N_NODES / 128, OUT_F / 128), 256, 0, stream>>>(
        z, Wt, bias, out);
}